// Round 2
// baseline (8393.092 us; speedup 1.0000x reference)
//
#include <hip/hip_runtime.h>
#include <math.h>

// Problem constants (setup_inputs): B=2, N=2048, C=1024, H=16, d=64
constexpr int Bc = 2;
constexpr int Nc = 2048;
constexpr int Cc = 1024;
constexpr int Hc = 16;
constexpr int Dc = 64;

// ---------------------------------------------------------------------------
// RoPE tables: cos/sin (N x 32), computed in fp64 for fidelity to reference
// ---------------------------------------------------------------------------
__global__ void rope_tables(float* __restrict__ cosT, float* __restrict__ sinT) {
    int idx = blockIdx.x * blockDim.x + threadIdx.x;   // N*32 = 65536
    if (idx >= Nc * 32) return;
    int n = idx >> 5;
    int j = idx & 31;
    double inv = pow(10000.0, -(double)j / 32.0);
    double ang = (double)n * inv;
    cosT[idx] = (float)cos(ang);
    sinT[idx] = (float)sin(ang);
}

// ---------------------------------------------------------------------------
// In-place RoPE on q and k inside the qkv buffer
// qkv layout: [B][N][3][H][D] row-major (row stride 3*C = 3072)
// ---------------------------------------------------------------------------
__global__ void rope_apply(float* __restrict__ qkv,
                           const float* __restrict__ cosT,
                           const float* __restrict__ sinT) {
    int idx = blockIdx.x * blockDim.x + threadIdx.x;   // B*N*H*32 = 2^21
    int j = idx & 31;
    int h = (idx >> 5) & (Hc - 1);
    int n = (idx >> 9) & (Nc - 1);
    int b = idx >> 20;
    if (b >= Bc) return;

    float c = cosT[n * 32 + j];
    float s = sinT[n * 32 + j];
    size_t rowbase = ((size_t)(b * Nc + n)) * (3 * Cc) + h * Dc;

    float* qp = qkv + rowbase;             // q slice
    float x1 = qp[j], x2 = qp[j + 32];
    qp[j]      = x1 * c - x2 * s;
    qp[j + 32] = x1 * s + x2 * c;

    float* kp = qkv + rowbase + Cc;        // k slice
    x1 = kp[j]; x2 = kp[j + 32];
    kp[j]      = x1 * c - x2 * s;
    kp[j + 32] = x1 * s + x2 * c;
}

// ---------------------------------------------------------------------------
// fp32 tiled GEMM: C = A(MxK) @ B(KxN) [+ bias], all row-major.
// 128x128 tile, BK=16, 256 threads, 8x8 micro-tile per thread.
// ---------------------------------------------------------------------------
constexpr int BM = 128, BN = 128, BK = 16;

__global__ __launch_bounds__(256) void gemm128(
    const float* __restrict__ A, const float* __restrict__ Bm,
    const float* __restrict__ bias, float* __restrict__ C,
    int M, int N, int K) {
    __shared__ float As[BK][BM + 4];
    __shared__ float Bs[BK][BN + 4];

    const int tid = threadIdx.x;
    const int tx = tid & 15;
    const int ty = tid >> 4;
    const int row0 = blockIdx.y * BM;
    const int col0 = blockIdx.x * BN;

    const int ar = tid >> 2;
    const int ac = (tid & 3) * 4;
    const int br = tid >> 4;
    const int bc = (tid & 15) * 8;

    float acc[8][8] = {};

    for (int k0 = 0; k0 < K; k0 += BK) {
        float4 a0 = *(const float4*)&A[(size_t)(row0 + ar) * K + k0 + ac];
        float4 a1 = *(const float4*)&A[(size_t)(row0 + ar + 64) * K + k0 + ac];
        float4 b0 = *(const float4*)&Bm[(size_t)(k0 + br) * N + col0 + bc];
        float4 b1 = *(const float4*)&Bm[(size_t)(k0 + br) * N + col0 + bc + 4];

        __syncthreads();
        As[ac + 0][ar] = a0.x; As[ac + 1][ar] = a0.y;
        As[ac + 2][ar] = a0.z; As[ac + 3][ar] = a0.w;
        As[ac + 0][ar + 64] = a1.x; As[ac + 1][ar + 64] = a1.y;
        As[ac + 2][ar + 64] = a1.z; As[ac + 3][ar + 64] = a1.w;
        *(float4*)&Bs[br][bc]     = b0;
        *(float4*)&Bs[br][bc + 4] = b1;
        __syncthreads();

        #pragma unroll
        for (int k = 0; k < BK; ++k) {
            float av[8], bv[8];
            *(float4*)&av[0] = *(const float4*)&As[k][ty * 8];
            *(float4*)&av[4] = *(const float4*)&As[k][ty * 8 + 4];
            *(float4*)&bv[0] = *(const float4*)&Bs[k][tx * 8];
            *(float4*)&bv[4] = *(const float4*)&Bs[k][tx * 8 + 4];
            #pragma unroll
            for (int i = 0; i < 8; ++i)
                #pragma unroll
                for (int j = 0; j < 8; ++j)
                    acc[i][j] = fmaf(av[i], bv[j], acc[i][j]);
        }
    }

    #pragma unroll
    for (int i = 0; i < 8; ++i) {
        int r = row0 + ty * 8 + i;
        #pragma unroll
        for (int j = 0; j < 8; j += 4) {
            int c = col0 + tx * 8 + j;
            float4 v = make_float4(acc[i][j], acc[i][j + 1],
                                   acc[i][j + 2], acc[i][j + 3]);
            if (bias) {
                v.x += bias[c];     v.y += bias[c + 1];
                v.z += bias[c + 2]; v.w += bias[c + 3];
            }
            *(float4*)&C[(size_t)r * N + c] = v;
        }
    }
}

// ---------------------------------------------------------------------------
// Flash attention v2: split-K x4 + dim-split x2 for occupancy.
// Block = 1024 threads = 128 q-rows x 4 key-splits x 2 dim-halves.
// tid = ((r*4 + sp)*2 + dh).  Each thread: 32 q/o dims in regs, 512 keys.
// LDS: K,V tiles [4 splits][32 keys][64 dims], split interleaved innermost
// so the 4 splits hit adjacent bank-groups (dh pairs 2-way = free).
// End: shfl_xor merge over splits (lane bits 1,2).
// ---------------------------------------------------------------------------
__global__ __launch_bounds__(1024) void flash_attn2(
    const float* __restrict__ qkv, float* __restrict__ out) {
    constexpr int C3 = 3 * Cc;
    const int bh = blockIdx.y;
    const int b = bh >> 4, h = bh & 15;
    const int tid = threadIdx.x;
    const int dh = tid & 1;          // dim half: dims [dh*32, dh*32+32)
    const int sp = (tid >> 1) & 3;   // key split: keys [sp*512, sp*512+512)
    const int r  = tid >> 3;         // 0..127 q-row within block
    const int qrow = blockIdx.x * 128 + r;
    const size_t base = (size_t)b * Nc * C3;

    // q half in registers (8 float4 = 32 floats)
    float4 q[8];
    {
        const float4* qp = (const float4*)(qkv + base + (size_t)qrow * C3
                                           + h * Dc + dh * 32);
        #pragma unroll
        for (int i = 0; i < 8; ++i) q[i] = qp[i];
    }
    float4 o[8];
    #pragma unroll
    for (int i = 0; i < 8; ++i) o[i] = make_float4(0.f, 0.f, 0.f, 0.f);
    float m = -1e30f, l = 0.f;

    __shared__ float4 Ks[2048];   // [(kk*16 + i)*4 + s], 32 KB
    __shared__ float4 Vs[2048];   // 32 KB

    // loader indices: each thread stages 2 K rows + 2 V rows per tile
    const int li  = tid & 15;          // dim float4 0..15
    const int lr  = (tid >> 4) & 31;   // tile row 0..31
    const int ls0 = tid >> 9;          // splits {ls0, ls0+2}
    const float* kbase = qkv + base + Cc + h * Dc;   // K slice; V = +Cc more

    float4 k0r, k1r, v0r, v1r;
    {   // prefetch tile 0
        size_t g0 = (size_t)(ls0 * 512 + lr) * C3;
        size_t g1 = (size_t)((ls0 + 2) * 512 + lr) * C3;
        k0r = *(const float4*)(kbase + g0 + li * 4);
        k1r = *(const float4*)(kbase + g1 + li * 4);
        v0r = *(const float4*)(kbase + Cc + g0 + li * 4);
        v1r = *(const float4*)(kbase + Cc + g1 + li * 4);
    }

    const int ldsw = (lr * 16 + li) * 4;
    for (int t = 0; t < 16; ++t) {
        __syncthreads();
        Ks[ldsw + ls0]     = k0r;
        Ks[ldsw + ls0 + 2] = k1r;
        Vs[ldsw + ls0]     = v0r;
        Vs[ldsw + ls0 + 2] = v1r;
        __syncthreads();
        if (t < 15) {   // prefetch next tile while computing this one
            int k0n = (t + 1) * 32;
            size_t g0 = (size_t)(ls0 * 512 + k0n + lr) * C3;
            size_t g1 = (size_t)((ls0 + 2) * 512 + k0n + lr) * C3;
            k0r = *(const float4*)(kbase + g0 + li * 4);
            k1r = *(const float4*)(kbase + g1 + li * 4);
            v0r = *(const float4*)(kbase + Cc + g0 + li * 4);
            v1r = *(const float4*)(kbase + Cc + g1 + li * 4);
        }

        for (int kk0 = 0; kk0 < 32; kk0 += 4) {
            float sc[4];
            #pragma unroll
            for (int kc = 0; kc < 4; ++kc) {
                const float4* kp = &Ks[((kk0 + kc) * 16 + dh * 8) * 4 + sp];
                float4 a = make_float4(0.f, 0.f, 0.f, 0.f);
                #pragma unroll
                for (int i = 0; i < 8; ++i) {
                    float4 kv = kp[i * 4];
                    a.x = fmaf(q[i].x, kv.x, a.x);
                    a.y = fmaf(q[i].y, kv.y, a.y);
                    a.z = fmaf(q[i].z, kv.z, a.z);
                    a.w = fmaf(q[i].w, kv.w, a.w);
                }
                float sum = (a.x + a.y) + (a.z + a.w);
                sum += __shfl_xor(sum, 1);       // combine dim halves
                sc[kc] = sum * 0.125f;
            }
            float mn = m;
            #pragma unroll
            for (int kc = 0; kc < 4; ++kc) mn = fmaxf(mn, sc[kc]);
            float corr = __expf(m - mn);
            float p[4];
            #pragma unroll
            for (int kc = 0; kc < 4; ++kc) p[kc] = __expf(sc[kc] - mn);
            l = l * corr + ((p[0] + p[1]) + (p[2] + p[3]));
            m = mn;
            #pragma unroll
            for (int i = 0; i < 8; ++i) {
                o[i].x *= corr; o[i].y *= corr; o[i].z *= corr; o[i].w *= corr;
            }
            #pragma unroll
            for (int kc = 0; kc < 4; ++kc) {
                const float4* vp = &Vs[((kk0 + kc) * 16 + dh * 8) * 4 + sp];
                float pk = p[kc];
                #pragma unroll
                for (int i = 0; i < 8; ++i) {
                    float4 vv = vp[i * 4];
                    o[i].x = fmaf(pk, vv.x, o[i].x);
                    o[i].y = fmaf(pk, vv.y, o[i].y);
                    o[i].z = fmaf(pk, vv.z, o[i].z);
                    o[i].w = fmaf(pk, vv.w, o[i].w);
                }
            }
        }
    }

    // merge the 4 key-splits (lane bits 1,2) via butterfly
    float M = m;
    M = fmaxf(M, __shfl_xor(M, 2));
    M = fmaxf(M, __shfl_xor(M, 4));
    float a = __expf(m - M);
    float lw = l * a;
    lw += __shfl_xor(lw, 2);
    lw += __shfl_xor(lw, 4);
    #pragma unroll
    for (int i = 0; i < 8; ++i) {
        o[i].x *= a; o[i].y *= a; o[i].z *= a; o[i].w *= a;
    }
    #pragma unroll
    for (int i = 0; i < 8; ++i) {
        o[i].x += __shfl_xor(o[i].x, 2);
        o[i].y += __shfl_xor(o[i].y, 2);
        o[i].z += __shfl_xor(o[i].z, 2);
        o[i].w += __shfl_xor(o[i].w, 2);
        o[i].x += __shfl_xor(o[i].x, 4);
        o[i].y += __shfl_xor(o[i].y, 4);
        o[i].z += __shfl_xor(o[i].z, 4);
        o[i].w += __shfl_xor(o[i].w, 4);
    }
    float inv = 1.f / lw;
    // lane sp writes float4s {sp*2, sp*2+1} of its 32-dim half (static selects)
    float4 w0 = o[0], w1 = o[1];
    if (sp == 1) { w0 = o[2]; w1 = o[3]; }
    if (sp == 2) { w0 = o[4]; w1 = o[5]; }
    if (sp == 3) { w0 = o[6]; w1 = o[7]; }
    w0.x *= inv; w0.y *= inv; w0.z *= inv; w0.w *= inv;
    w1.x *= inv; w1.y *= inv; w1.z *= inv; w1.w *= inv;
    float* op = out + ((size_t)(b * Nc + qrow)) * Cc + h * Dc + dh * 32 + sp * 8;
    ((float4*)op)[0] = w0;
    ((float4*)op)[1] = w1;
}

// ---------------------------------------------------------------------------
extern "C" void kernel_launch(void* const* d_in, const int* in_sizes, int n_in,
                              void* d_out, int out_size, void* d_ws, size_t ws_size,
                              hipStream_t stream) {
    const float* x      = (const float*)d_in[0];   // (2,2048,1024)
    const float* w_qkv  = (const float*)d_in[1];   // (1024,3072)
    const float* w_proj = (const float*)d_in[2];   // (1024,1024)
    const float* b_proj = (const float*)d_in[3];   // (1024,)
    float* out = (float*)d_out;                    // (2,2048,1024)

    float* ws = (float*)d_ws;
    float* qkv     = ws;                               // 4096*3072 floats
    float* attnout = ws + (size_t)4096 * 3072;         // 4096*1024 floats
    float* cosT    = attnout + (size_t)4096 * 1024;    // 65,536 floats
    float* sinT    = cosT + Nc * 32;                   // 65,536 floats

    // 1. RoPE tables
    rope_tables<<<(Nc * 32 + 255) / 256, 256, 0, stream>>>(cosT, sinT);

    // 2. qkv = x @ w_qkv   (4096 x 3072 x 1024)
    gemm128<<<dim3(3072 / BN, 4096 / BM), 256, 0, stream>>>(
        x, w_qkv, nullptr, qkv, 4096, 3072, 1024);

    // 3. RoPE on q,k in place
    rope_apply<<<(Bc * Nc * Hc * 32) / 256, 256, 0, stream>>>(qkv, cosT, sinT);

    // 4. attention -> attnout [B][N][C]
    flash_attn2<<<dim3(Nc / 128, Bc * Hc), 1024, 0, stream>>>(qkv, attnout);

    // 5. out = attnout @ w_proj + b_proj   (4096 x 1024 x 1024)
    gemm128<<<dim3(1024 / BN, 4096 / BM), 256, 0, stream>>>(
        attnout, w_proj, b_proj, out, 4096, 1024, 1024);
}

// Round 3
// 1456.993 us; speedup vs baseline: 5.7606x; 5.7606x over previous
//
#include <hip/hip_runtime.h>
#include <math.h>

// Problem constants (setup_inputs): B=2, N=2048, C=1024, H=16, d=64
constexpr int Bc = 2;
constexpr int Nc = 2048;
constexpr int Cc = 1024;
constexpr int Hc = 16;
constexpr int Dc = 64;

// ---------------------------------------------------------------------------
// RoPE tables: cos/sin (N x 32), fp64 for fidelity
// ---------------------------------------------------------------------------
__global__ void rope_tables(float* __restrict__ cosT, float* __restrict__ sinT) {
    int idx = blockIdx.x * blockDim.x + threadIdx.x;   // N*32 = 65536
    if (idx >= Nc * 32) return;
    int n = idx >> 5;
    int j = idx & 31;
    double inv = pow(10000.0, -(double)j / 32.0);
    double ang = (double)n * inv;
    cosT[idx] = (float)cos(ang);
    sinT[idx] = (float)sin(ang);
}

// ---------------------------------------------------------------------------
// In-place RoPE on q and k inside the qkv buffer  [B][N][3][H][D]
// ---------------------------------------------------------------------------
__global__ void rope_apply(float* __restrict__ qkv,
                           const float* __restrict__ cosT,
                           const float* __restrict__ sinT) {
    int idx = blockIdx.x * blockDim.x + threadIdx.x;   // B*N*H*32
    int j = idx & 31;
    int h = (idx >> 5) & (Hc - 1);
    int n = (idx >> 9) & (Nc - 1);
    int b = idx >> 20;
    if (b >= Bc) return;

    float c = cosT[n * 32 + j];
    float s = sinT[n * 32 + j];
    size_t rowbase = ((size_t)(b * Nc + n)) * (3 * Cc) + h * Dc;

    float* qp = qkv + rowbase;
    float x1 = qp[j], x2 = qp[j + 32];
    qp[j]      = x1 * c - x2 * s;
    qp[j + 32] = x1 * s + x2 * c;

    float* kp = qkv + rowbase + Cc;
    x1 = kp[j]; x2 = kp[j + 32];
    kp[j]      = x1 * c - x2 * s;
    kp[j + 32] = x1 * s + x2 * c;
}

// ---------------------------------------------------------------------------
// fp32 tiled GEMM: C = A(MxK) @ B(KxN) [+ bias], row-major. 128x128x16.
// ---------------------------------------------------------------------------
constexpr int BM = 128, BN = 128, BK = 16;

__global__ __launch_bounds__(256) void gemm128(
    const float* __restrict__ A, const float* __restrict__ Bm,
    const float* __restrict__ bias, float* __restrict__ C,
    int M, int N, int K) {
    __shared__ float As[BK][BM + 4];
    __shared__ float Bs[BK][BN + 4];

    const int tid = threadIdx.x;
    const int tx = tid & 15;
    const int ty = tid >> 4;
    const int row0 = blockIdx.y * BM;
    const int col0 = blockIdx.x * BN;

    const int ar = tid >> 2;
    const int ac = (tid & 3) * 4;
    const int br = tid >> 4;
    const int bc = (tid & 15) * 8;

    float acc[8][8] = {};

    for (int k0 = 0; k0 < K; k0 += BK) {
        float4 a0 = *(const float4*)&A[(size_t)(row0 + ar) * K + k0 + ac];
        float4 a1 = *(const float4*)&A[(size_t)(row0 + ar + 64) * K + k0 + ac];
        float4 b0 = *(const float4*)&Bm[(size_t)(k0 + br) * N + col0 + bc];
        float4 b1 = *(const float4*)&Bm[(size_t)(k0 + br) * N + col0 + bc + 4];

        __syncthreads();
        As[ac + 0][ar] = a0.x; As[ac + 1][ar] = a0.y;
        As[ac + 2][ar] = a0.z; As[ac + 3][ar] = a0.w;
        As[ac + 0][ar + 64] = a1.x; As[ac + 1][ar + 64] = a1.y;
        As[ac + 2][ar + 64] = a1.z; As[ac + 3][ar + 64] = a1.w;
        *(float4*)&Bs[br][bc]     = b0;
        *(float4*)&Bs[br][bc + 4] = b1;
        __syncthreads();

        #pragma unroll
        for (int k = 0; k < BK; ++k) {
            float av[8], bv[8];
            *(float4*)&av[0] = *(const float4*)&As[k][ty * 8];
            *(float4*)&av[4] = *(const float4*)&As[k][ty * 8 + 4];
            *(float4*)&bv[0] = *(const float4*)&Bs[k][tx * 8];
            *(float4*)&bv[4] = *(const float4*)&Bs[k][tx * 8 + 4];
            #pragma unroll
            for (int i = 0; i < 8; ++i)
                #pragma unroll
                for (int j = 0; j < 8; ++j)
                    acc[i][j] = fmaf(av[i], bv[j], acc[i][j]);
        }
    }

    #pragma unroll
    for (int i = 0; i < 8; ++i) {
        int r = row0 + ty * 8 + i;
        #pragma unroll
        for (int j = 0; j < 8; j += 4) {
            int c = col0 + tx * 8 + j;
            float4 v = make_float4(acc[i][j], acc[i][j + 1],
                                   acc[i][j + 2], acc[i][j + 3]);
            if (bias) {
                v.x += bias[c];     v.y += bias[c + 1];
                v.z += bias[c + 2]; v.w += bias[c + 3];
            }
            *(float4*)&C[(size_t)r * N + c] = v;
        }
    }
}

// ---------------------------------------------------------------------------
// Flash attention v3: grid split-K. One q-row per thread (R1 structure, no
// spill), nsplit dispatch slices of the key range write UNNORMALIZED partials
// (o, m, l); attn_combine merges. Inner loop chunks 2 keys to amortize the
// o-rescale. LDS: 64-key K/V tiles, broadcast reads (0 conflicts in R1).
// ---------------------------------------------------------------------------
constexpr int KT = 64;

__global__ __launch_bounds__(256) void flash_attn3(
    const float* __restrict__ qkv, float* __restrict__ part_o,
    float* __restrict__ part_ml, int nsplit) {
    constexpr int C3 = 3 * Cc;
    const int bh = blockIdx.y;
    const int b = bh >> 4, h = bh & 15;
    const int sp = blockIdx.z;
    const int qrow = blockIdx.x * 256 + threadIdx.x;
    const int kper = Nc / nsplit;
    const int kbeg = sp * kper;
    const size_t base = (size_t)b * Nc * C3;

    float4 q[Dc / 4];
    {
        const float4* qp = (const float4*)(qkv + base + (size_t)qrow * C3 + h * Dc);
        #pragma unroll
        for (int i = 0; i < Dc / 4; ++i) q[i] = qp[i];
    }
    float4 o[Dc / 4];
    #pragma unroll
    for (int i = 0; i < Dc / 4; ++i) o[i] = make_float4(0.f, 0.f, 0.f, 0.f);
    float m = -1e30f, l = 0.f;

    __shared__ float4 Ks[KT * 16];   // 16 KB
    __shared__ float4 Vs[KT * 16];   // 16 KB

    for (int t = 0; t < kper; t += KT) {
        __syncthreads();
        #pragma unroll
        for (int i = 0; i < 4; ++i) {
            int idx = threadIdx.x + i * 256;     // 0..1023
            int r = idx >> 4;
            int c = idx & 15;
            const float* kp = qkv + base + (size_t)(kbeg + t + r) * C3 + Cc + h * Dc;
            Ks[r * 16 + c] = ((const float4*)kp)[c];
            Vs[r * 16 + c] = ((const float4*)(kp + Cc))[c];
        }
        __syncthreads();

        for (int kk = 0; kk < KT; kk += 2) {
            float4 a0 = make_float4(0.f, 0.f, 0.f, 0.f);
            float4 a1 = make_float4(0.f, 0.f, 0.f, 0.f);
            #pragma unroll
            for (int i = 0; i < 16; ++i) {
                float4 k0 = Ks[kk * 16 + i];
                float4 k1 = Ks[kk * 16 + 16 + i];
                a0.x = fmaf(q[i].x, k0.x, a0.x);
                a0.y = fmaf(q[i].y, k0.y, a0.y);
                a0.z = fmaf(q[i].z, k0.z, a0.z);
                a0.w = fmaf(q[i].w, k0.w, a0.w);
                a1.x = fmaf(q[i].x, k1.x, a1.x);
                a1.y = fmaf(q[i].y, k1.y, a1.y);
                a1.z = fmaf(q[i].z, k1.z, a1.z);
                a1.w = fmaf(q[i].w, k1.w, a1.w);
            }
            float s0 = ((a0.x + a0.y) + (a0.z + a0.w)) * 0.125f;
            float s1 = ((a1.x + a1.y) + (a1.z + a1.w)) * 0.125f;
            float mn = fmaxf(m, fmaxf(s0, s1));
            float corr = __expf(m - mn);
            float p0 = __expf(s0 - mn);
            float p1 = __expf(s1 - mn);
            l = l * corr + p0 + p1;
            m = mn;
            #pragma unroll
            for (int i = 0; i < 16; ++i) {
                float4 v0 = Vs[kk * 16 + i];
                float4 v1 = Vs[kk * 16 + 16 + i];
                float4 t4 = o[i];
                t4.x = t4.x * corr; t4.y = t4.y * corr;
                t4.z = t4.z * corr; t4.w = t4.w * corr;
                t4.x = fmaf(p0, v0.x, t4.x); t4.y = fmaf(p0, v0.y, t4.y);
                t4.z = fmaf(p0, v0.z, t4.z); t4.w = fmaf(p0, v0.w, t4.w);
                t4.x = fmaf(p1, v1.x, t4.x); t4.y = fmaf(p1, v1.y, t4.y);
                t4.z = fmaf(p1, v1.z, t4.z); t4.w = fmaf(p1, v1.w, t4.w);
                o[i] = t4;
            }
        }
    }

    // write unnormalized partial
    const size_t row_g = (size_t)bh * Nc + qrow;          // 0..65535
    float4* po = (float4*)(part_o + ((size_t)sp * (Bc * Hc * Nc) + row_g) * Dc);
    #pragma unroll
    for (int i = 0; i < Dc / 4; ++i) po[i] = o[i];
    float* pm = part_ml + ((size_t)sp * (Bc * Hc * Nc) + row_g) * 2;
    pm[0] = m;
    pm[1] = l;
}

// ---------------------------------------------------------------------------
// Merge nsplit partials, normalize, scatter to attnout [B][N][H*D]
// One thread per (row, 4-dim group): 65536 * 16 threads.
// ---------------------------------------------------------------------------
__global__ __launch_bounds__(256) void attn_combine(
    const float* __restrict__ part_o, const float* __restrict__ part_ml,
    float* __restrict__ attnout, int nsplit) {
    const int t = blockIdx.x * 256 + threadIdx.x;
    const int row = t >> 4;          // bh*2048 + n
    const int c4 = t & 15;
    const int bh = row >> 11;
    const int n = row & 2047;
    const int b = bh >> 4, h = bh & 15;
    constexpr int RWS = Bc * Hc * Nc;   // 65536

    float M = -1e30f;
    for (int s = 0; s < nsplit; ++s)
        M = fmaxf(M, part_ml[((size_t)s * RWS + row) * 2]);

    float L = 0.f;
    float4 acc = make_float4(0.f, 0.f, 0.f, 0.f);
    for (int s = 0; s < nsplit; ++s) {
        const float* pm = part_ml + ((size_t)s * RWS + row) * 2;
        float w = __expf(pm[0] - M);
        L += pm[1] * w;
        float4 v = ((const float4*)(part_o + ((size_t)s * RWS + row) * Dc))[c4];
        acc.x = fmaf(w, v.x, acc.x);
        acc.y = fmaf(w, v.y, acc.y);
        acc.z = fmaf(w, v.z, acc.z);
        acc.w = fmaf(w, v.w, acc.w);
    }
    float inv = 1.f / L;
    acc.x *= inv; acc.y *= inv; acc.z *= inv; acc.w *= inv;
    float* op = attnout + ((size_t)(b * Nc + n)) * Cc + h * Dc + c4 * 4;
    *(float4*)op = acc;
}

// ---------------------------------------------------------------------------
extern "C" void kernel_launch(void* const* d_in, const int* in_sizes, int n_in,
                              void* d_out, int out_size, void* d_ws, size_t ws_size,
                              hipStream_t stream) {
    const float* x      = (const float*)d_in[0];   // (2,2048,1024)
    const float* w_qkv  = (const float*)d_in[1];   // (1024,3072)
    const float* w_proj = (const float*)d_in[2];   // (1024,1024)
    const float* b_proj = (const float*)d_in[3];   // (1024,)
    float* out = (float*)d_out;                    // (2,2048,1024)

    float* ws = (float*)d_ws;
    float* qkv     = ws;                               // 12,582,912 floats
    float* attnout = qkv + (size_t)4096 * 3072;        //  4,194,304 floats
    float* cosT    = attnout + (size_t)4096 * 1024;    //     65,536 floats
    float* sinT    = cosT + Nc * 32;                   //     65,536 floats
    float* part_o  = sinT + Nc * 32;                   // S*65536*64 floats
    constexpr size_t RWS = (size_t)Bc * Hc * Nc;       // 65536 rows

    // pick split count by available workspace
    size_t base_f = (size_t)4096 * 3072 + (size_t)4096 * 1024 + 2 * Nc * 32;
    size_t avail_f = ws_size / 4 > base_f ? ws_size / 4 - base_f : 0;
    int nsplit = 1;
    if (avail_f >= 4 * RWS * (Dc + 2)) nsplit = 4;
    else if (avail_f >= 2 * RWS * (Dc + 2)) nsplit = 2;
    float* part_ml = part_o + (size_t)nsplit * RWS * Dc;

    // 1. RoPE tables
    rope_tables<<<(Nc * 32 + 255) / 256, 256, 0, stream>>>(cosT, sinT);

    // 2. qkv = x @ w_qkv   (4096 x 3072 x 1024)
    gemm128<<<dim3(3072 / BN, 4096 / BM), 256, 0, stream>>>(
        x, w_qkv, nullptr, qkv, 4096, 3072, 1024);

    // 3. RoPE on q,k in place
    rope_apply<<<(Bc * Nc * Hc * 32) / 256, 256, 0, stream>>>(qkv, cosT, sinT);

    // 4. attention partials + combine -> attnout [B][N][C]
    flash_attn3<<<dim3(Nc / 256, Bc * Hc, nsplit), 256, 0, stream>>>(
        qkv, part_o, part_ml, nsplit);
    attn_combine<<<(RWS * 16) / 256, 256, 0, stream>>>(
        part_o, part_ml, attnout, nsplit);

    // 5. out = attnout @ w_proj + b_proj   (4096 x 1024 x 1024)
    gemm128<<<dim3(1024 / BN, 4096 / BM), 256, 0, stream>>>(
        attnout, w_proj, b_proj, out, 4096, 1024, 1024);
}

// Round 4
// 714.156 us; speedup vs baseline: 11.7525x; 2.0402x over previous
//
#include <hip/hip_runtime.h>
#include <math.h>

// Problem constants: B=2, N=2048, C=1024, H=16, d=64
constexpr int Bc = 2;
constexpr int Nc = 2048;
constexpr int Cc = 1024;
constexpr int Hc = 16;
constexpr int Dc = 64;

typedef __bf16 bf16x8 __attribute__((ext_vector_type(8)));
typedef float  f32x4  __attribute__((ext_vector_type(4)));

// ---------------------------------------------------------------------------
// RoPE tables: cos/sin (N x 32), fp64 for fidelity
// ---------------------------------------------------------------------------
__global__ void rope_tables(float* __restrict__ cosT, float* __restrict__ sinT) {
    int idx = blockIdx.x * blockDim.x + threadIdx.x;   // N*32 = 65536
    if (idx >= Nc * 32) return;
    int n = idx >> 5;
    int j = idx & 31;
    double inv = pow(10000.0, -(double)j / 32.0);
    double ang = (double)n * inv;
    cosT[idx] = (float)cos(ang);
    sinT[idx] = (float)sin(ang);
}

// ---------------------------------------------------------------------------
// fp32 tiled GEMM: C = A(MxK) @ B(KxN) [+ bias], row-major. 128x128x16.
// ---------------------------------------------------------------------------
constexpr int BM = 128, BN = 128, BK = 16;

__global__ __launch_bounds__(256) void gemm128(
    const float* __restrict__ A, const float* __restrict__ Bm,
    const float* __restrict__ bias, float* __restrict__ C,
    int M, int N, int K) {
    __shared__ float As[BK][BM + 4];
    __shared__ float Bs[BK][BN + 4];

    const int tid = threadIdx.x;
    const int tx = tid & 15;
    const int ty = tid >> 4;
    const int row0 = blockIdx.y * BM;
    const int col0 = blockIdx.x * BN;

    const int ar = tid >> 2;
    const int ac = (tid & 3) * 4;
    const int br = tid >> 4;
    const int bc = (tid & 15) * 8;

    float acc[8][8] = {};

    for (int k0 = 0; k0 < K; k0 += BK) {
        float4 a0 = *(const float4*)&A[(size_t)(row0 + ar) * K + k0 + ac];
        float4 a1 = *(const float4*)&A[(size_t)(row0 + ar + 64) * K + k0 + ac];
        float4 b0 = *(const float4*)&Bm[(size_t)(k0 + br) * N + col0 + bc];
        float4 b1 = *(const float4*)&Bm[(size_t)(k0 + br) * N + col0 + bc + 4];

        __syncthreads();
        As[ac + 0][ar] = a0.x; As[ac + 1][ar] = a0.y;
        As[ac + 2][ar] = a0.z; As[ac + 3][ar] = a0.w;
        As[ac + 0][ar + 64] = a1.x; As[ac + 1][ar + 64] = a1.y;
        As[ac + 2][ar + 64] = a1.z; As[ac + 3][ar + 64] = a1.w;
        *(float4*)&Bs[br][bc]     = b0;
        *(float4*)&Bs[br][bc + 4] = b1;
        __syncthreads();

        #pragma unroll
        for (int k = 0; k < BK; ++k) {
            float av[8], bv[8];
            *(float4*)&av[0] = *(const float4*)&As[k][ty * 8];
            *(float4*)&av[4] = *(const float4*)&As[k][ty * 8 + 4];
            *(float4*)&bv[0] = *(const float4*)&Bs[k][tx * 8];
            *(float4*)&bv[4] = *(const float4*)&Bs[k][tx * 8 + 4];
            #pragma unroll
            for (int i = 0; i < 8; ++i)
                #pragma unroll
                for (int j = 0; j < 8; ++j)
                    acc[i][j] = fmaf(av[i], bv[j], acc[i][j]);
        }
    }

    #pragma unroll
    for (int i = 0; i < 8; ++i) {
        int r = row0 + ty * 8 + i;
        #pragma unroll
        for (int j = 0; j < 8; j += 4) {
            int c = col0 + tx * 8 + j;
            float4 v = make_float4(acc[i][j], acc[i][j + 1],
                                   acc[i][j + 2], acc[i][j + 3]);
            if (bias) {
                v.x += bias[c];     v.y += bias[c + 1];
                v.z += bias[c + 2]; v.w += bias[c + 3];
            }
            *(float4*)&C[(size_t)r * N + c] = v;
        }
    }
}

// ---------------------------------------------------------------------------
// rope_pack: read fp32 qkv [B][N][3][H][D], apply RoPE to q,k, fold the 1/8
// softmax scale into q, split q,k into bf16 hi+lo, write:
//   Qh,Ql,Kh,Kl: [BH][N][64] bf16     Vt: [BH][64][N] bf16 (transposed)
// grid (32 ntiles, 32 bh), 256 threads; V transposed via LDS 64x64 tile.
// ---------------------------------------------------------------------------
__global__ __launch_bounds__(256) void rope_pack(
    const float* __restrict__ qkv,
    const float* __restrict__ cosT, const float* __restrict__ sinT,
    __bf16* __restrict__ Qh, __bf16* __restrict__ Ql,
    __bf16* __restrict__ Kh, __bf16* __restrict__ Kl,
    __bf16* __restrict__ Vt) {
    constexpr int C3 = 3 * Cc;
    const int bh = blockIdx.y;
    const int b = bh >> 4, h = bh & 15;
    const int n0 = blockIdx.x * 64;
    const int tid = threadIdx.x;

    // --- RoPE + hi/lo split for q,k: 64 rows x 32 pairs ---
    const int j = tid & 31, rr = tid >> 5;     // 8 rows per pass
    #pragma unroll 2
    for (int pass = 0; pass < 8; ++pass) {
        int n = n0 + pass * 8 + rr;
        const float* row = qkv + ((size_t)(b * Nc + n)) * C3 + h * Dc;
        float c = cosT[n * 32 + j];
        float s = sinT[n * 32 + j];
        float q1 = row[j], q2 = row[j + 32];
        float k1 = row[Cc + j], k2 = row[Cc + j + 32];
        float qa = (q1 * c - q2 * s) * 0.125f;     // scale folded into q
        float qb = (q1 * s + q2 * c) * 0.125f;
        float ka = k1 * c - k2 * s;
        float kb = k1 * s + k2 * c;
        size_t o = ((size_t)bh * Nc + n) * Dc;
        __bf16 t;
        t = (__bf16)qa; Qh[o + j]      = t; Ql[o + j]      = (__bf16)(qa - (float)t);
        t = (__bf16)qb; Qh[o + j + 32] = t; Ql[o + j + 32] = (__bf16)(qb - (float)t);
        t = (__bf16)ka; Kh[o + j]      = t; Kl[o + j]      = (__bf16)(ka - (float)t);
        t = (__bf16)kb; Kh[o + j + 32] = t; Kl[o + j + 32] = (__bf16)(kb - (float)t);
    }

    // --- V transpose: [n][d] -> Vt[d][n] via LDS ---
    __shared__ float vt[64][65];
    const int f = tid & 63, r4 = tid >> 6;
    #pragma unroll 4
    for (int pass = 0; pass < 16; ++pass) {
        int i = pass * 4 + r4;
        vt[f][i] = qkv[((size_t)(b * Nc + n0 + i)) * C3 + 2 * Cc + h * Dc + f];
    }
    __syncthreads();
    #pragma unroll 4
    for (int pass = 0; pass < 16; ++pass) {
        int feat = pass * 4 + r4;
        Vt[((size_t)bh * Dc + feat) * Nc + n0 + f] = (__bf16)vt[feat][f];
    }
}

// ---------------------------------------------------------------------------
// attn_mfma: flash attention on matrix cores.
// Block = 256 thr = 4 waves; each wave owns 32 q-rows; block covers 128 rows
// of one (b,h). K-loop tiles 64 keys. QK^T = 3 MFMA passes (qh*kh + qh*kl +
// ql*kh), online softmax in C-layout, P routed C->A layout through per-wave
// LDS (row stride 72 bf16 = 144 B, 16B-aligned rows), PV in bf16 MFMA.
// No __syncthreads in the K-loop (wave-private LDS).
// Layout facts (HW-verified): C/D row=(lane>>4)*4+reg, col=lane&15;
// A-frag A[m=lane&15][k=(lane>>4)*8+j]; B-frag B[k=(lane>>4)*8+j][n=lane&15].
// ---------------------------------------------------------------------------
#define MFMA16(A, B, C) __builtin_amdgcn_mfma_f32_16x16x32_bf16(A, B, C, 0, 0, 0)

__global__ __launch_bounds__(256) void attn_mfma(
    const __bf16* __restrict__ Qh, const __bf16* __restrict__ Ql,
    const __bf16* __restrict__ Kh, const __bf16* __restrict__ Kl,
    const __bf16* __restrict__ Vt, float* __restrict__ attnout) {
    const int bh = blockIdx.y;
    const int b = bh >> 4, h = bh & 15;
    const int q0 = blockIdx.x * 128;
    const int w = threadIdx.x >> 6;
    const int lane = threadIdx.x & 63;
    const int l16 = lane & 15, quad = lane >> 4;

    const __bf16* Qhb = Qh + (size_t)bh * Nc * Dc;
    const __bf16* Qlb = Ql + (size_t)bh * Nc * Dc;
    const __bf16* Khb = Kh + (size_t)bh * Nc * Dc;
    const __bf16* Klb = Kl + (size_t)bh * Nc * Dc;
    const __bf16* Vtb = Vt + (size_t)bh * Dc * Nc;

    // Q fragments (A-operand), loaded once: [rowtile mi][kstep ks]
    bf16x8 qh[2][2], ql[2][2];
    #pragma unroll
    for (int mi = 0; mi < 2; ++mi)
        #pragma unroll
        for (int ks = 0; ks < 2; ++ks) {
            size_t off = (size_t)(q0 + w * 32 + mi * 16 + l16) * Dc + ks * 32 + quad * 8;
            qh[mi][ks] = *(const bf16x8*)(Qhb + off);
            ql[mi][ks] = *(const bf16x8*)(Qlb + off);
        }

    f32x4 Oa[2][4];
    #pragma unroll
    for (int mi = 0; mi < 2; ++mi)
        #pragma unroll
        for (int ni = 0; ni < 4; ++ni) Oa[mi][ni] = (f32x4){0.f, 0.f, 0.f, 0.f};
    float mrow[2][4], lrow[2][4];
    #pragma unroll
    for (int mi = 0; mi < 2; ++mi)
        #pragma unroll
        for (int r = 0; r < 4; ++r) { mrow[mi][r] = -1e30f; lrow[mi][r] = 0.f; }

    __shared__ __bf16 Plds[4][32 * 72];   // per-wave 32 rows x 64 keys, stride 72
    __bf16* Pw = Plds[w];

    for (int t = 0; t < Nc; t += 64) {
        // ---- S = Qs . K^T  (3-way split-bf16), 64 keys = 4 keytiles ----
        f32x4 S[2][4];
        #pragma unroll
        for (int mi = 0; mi < 2; ++mi)
            #pragma unroll
            for (int kt = 0; kt < 4; ++kt) S[mi][kt] = (f32x4){0.f, 0.f, 0.f, 0.f};

        #pragma unroll
        for (int kt = 0; kt < 4; ++kt) {
            size_t kb = (size_t)(t + kt * 16 + l16) * Dc + quad * 8;
            bf16x8 kh0 = *(const bf16x8*)(Khb + kb);
            bf16x8 kh1 = *(const bf16x8*)(Khb + kb + 32);
            bf16x8 kl0 = *(const bf16x8*)(Klb + kb);
            bf16x8 kl1 = *(const bf16x8*)(Klb + kb + 32);
            #pragma unroll
            for (int mi = 0; mi < 2; ++mi) {
                S[mi][kt] = MFMA16(ql[mi][0], kh0, S[mi][kt]);
                S[mi][kt] = MFMA16(qh[mi][0], kl0, S[mi][kt]);
                S[mi][kt] = MFMA16(qh[mi][0], kh0, S[mi][kt]);
                S[mi][kt] = MFMA16(ql[mi][1], kh1, S[mi][kt]);
                S[mi][kt] = MFMA16(qh[mi][1], kl1, S[mi][kt]);
                S[mi][kt] = MFMA16(qh[mi][1], kh1, S[mi][kt]);
            }
        }

        // ---- online softmax (C-layout: row = quad*4+r, col = kt*16+l16) ----
        float corr[2][4], psum[2][4];
        #pragma unroll
        for (int mi = 0; mi < 2; ++mi)
            #pragma unroll
            for (int r = 0; r < 4; ++r) {
                float mx = S[mi][0][r];
                mx = fmaxf(mx, S[mi][1][r]);
                mx = fmaxf(mx, S[mi][2][r]);
                mx = fmaxf(mx, S[mi][3][r]);
                mx = fmaxf(mx, __shfl_xor(mx, 1));
                mx = fmaxf(mx, __shfl_xor(mx, 2));
                mx = fmaxf(mx, __shfl_xor(mx, 4));
                mx = fmaxf(mx, __shfl_xor(mx, 8));
                float mn = fmaxf(mrow[mi][r], mx);
                corr[mi][r] = __expf(mrow[mi][r] - mn);
                mrow[mi][r] = mn;
                psum[mi][r] = 0.f;
            }

        // p = exp(s-m), round to bf16 (l summed from rounded p), stash in LDS
        #pragma unroll
        for (int mi = 0; mi < 2; ++mi)
            #pragma unroll
            for (int kt = 0; kt < 4; ++kt)
                #pragma unroll
                for (int r = 0; r < 4; ++r) {
                    float p = __expf(S[mi][kt][r] - mrow[mi][r]);
                    __bf16 pb = (__bf16)p;
                    Pw[(mi * 16 + quad * 4 + r) * 72 + kt * 16 + l16] = pb;
                    psum[mi][r] += (float)pb;
                }

        #pragma unroll
        for (int mi = 0; mi < 2; ++mi)
            #pragma unroll
            for (int r = 0; r < 4; ++r) {
                float ps = psum[mi][r];
                ps += __shfl_xor(ps, 1);
                ps += __shfl_xor(ps, 2);
                ps += __shfl_xor(ps, 4);
                ps += __shfl_xor(ps, 8);
                lrow[mi][r] = lrow[mi][r] * corr[mi][r] + ps;
            }

        // rescale O
        #pragma unroll
        for (int mi = 0; mi < 2; ++mi)
            #pragma unroll
            for (int ni = 0; ni < 4; ++ni)
                #pragma unroll
                for (int r = 0; r < 4; ++r) Oa[mi][ni][r] *= corr[mi][r];

        // ---- O += P . V  (P A-frags from LDS, V B-frags from Vt) ----
        #pragma unroll
        for (int ks2 = 0; ks2 < 2; ++ks2) {
            bf16x8 Pf[2];
            #pragma unroll
            for (int mi = 0; mi < 2; ++mi)
                Pf[mi] = *(const bf16x8*)&Pw[(mi * 16 + l16) * 72 + ks2 * 32 + quad * 8];
            #pragma unroll
            for (int ni = 0; ni < 4; ++ni) {
                bf16x8 vf = *(const bf16x8*)(Vtb + (size_t)(ni * 16 + l16) * Nc
                                             + t + ks2 * 32 + quad * 8);
                #pragma unroll
                for (int mi = 0; mi < 2; ++mi)
                    Oa[mi][ni] = MFMA16(Pf[mi], vf, Oa[mi][ni]);
            }
        }
    }

    // ---- epilogue: normalize, write attnout [B][N][C] fp32 ----
    #pragma unroll
    for (int mi = 0; mi < 2; ++mi) {
        float inv[4];
        #pragma unroll
        for (int r = 0; r < 4; ++r) inv[r] = 1.f / lrow[mi][r];
        #pragma unroll
        for (int ni = 0; ni < 4; ++ni)
            #pragma unroll
            for (int r = 0; r < 4; ++r) {
                int row = q0 + w * 32 + mi * 16 + quad * 4 + r;
                attnout[((size_t)(b * Nc + row)) * Cc + h * Dc + ni * 16 + l16]
                    = Oa[mi][ni][r] * inv[r];
            }
    }
}

// ---------------------------------------------------------------------------
extern "C" void kernel_launch(void* const* d_in, const int* in_sizes, int n_in,
                              void* d_out, int out_size, void* d_ws, size_t ws_size,
                              hipStream_t stream) {
    const float* x      = (const float*)d_in[0];   // (2,2048,1024)
    const float* w_qkv  = (const float*)d_in[1];   // (1024,3072)
    const float* w_proj = (const float*)d_in[2];   // (1024,1024)
    const float* b_proj = (const float*)d_in[3];   // (1024,)
    float* out = (float*)d_out;                    // (2,2048,1024)

    float* ws = (float*)d_ws;
    float* qkv     = ws;                               // 12,582,912 f
    float* attnout = qkv + (size_t)4096 * 3072;        //  4,194,304 f
    float* cosT    = attnout + (size_t)4096 * 1024;    //     65,536 f
    float* sinT    = cosT + Nc * 32;                   //     65,536 f
    __bf16* bfbase = (__bf16*)(sinT + Nc * 32);
    constexpr size_t HS = (size_t)Bc * Hc * Nc * Dc;   // 4,194,304 elems
    __bf16* Qh = bfbase;
    __bf16* Ql = Qh + HS;
    __bf16* Kh = Ql + HS;
    __bf16* Kl = Kh + HS;
    __bf16* Vt = Kl + HS;                              // total bf16: 41.9 MB

    // 1. RoPE tables
    rope_tables<<<(Nc * 32 + 255) / 256, 256, 0, stream>>>(cosT, sinT);

    // 2. qkv = x @ w_qkv   (4096 x 3072 x 1024), fp32
    gemm128<<<dim3(3072 / BN, 4096 / BM), 256, 0, stream>>>(
        x, w_qkv, nullptr, qkv, 4096, 3072, 1024);

    // 3. RoPE + bf16 hi/lo split + V transpose
    rope_pack<<<dim3(Nc / 64, Bc * Hc), 256, 0, stream>>>(
        qkv, cosT, sinT, Qh, Ql, Kh, Kl, Vt);

    // 4. MFMA flash attention -> attnout [B][N][C] fp32
    attn_mfma<<<dim3(Nc / 128, Bc * Hc), 256, 0, stream>>>(
        Qh, Ql, Kh, Kl, Vt, attnout);

    // 5. out = attnout @ w_proj + b_proj   (4096 x 1024 x 1024), fp32
    gemm128<<<dim3(1024 / BN, 4096 / BM), 256, 0, stream>>>(
        attnout, w_proj, b_proj, out, 4096, 1024, 1024);
}

// Round 5
// 444.050 us; speedup vs baseline: 18.9012x; 1.6083x over previous
//
#include <hip/hip_runtime.h>
#include <math.h>

// Problem constants: B=2, N=2048, C=1024, H=16, d=64
constexpr int Bc = 2;
constexpr int Nc = 2048;
constexpr int Cc = 1024;
constexpr int Hc = 16;
constexpr int Dc = 64;

typedef __bf16 bf16x8 __attribute__((ext_vector_type(8)));
typedef __bf16 bf16x4 __attribute__((ext_vector_type(4)));
typedef float  f32x4  __attribute__((ext_vector_type(4)));

// async global->LDS, 16 B per lane; LDS dest = uniform base + lane*16
__device__ __forceinline__ void gload_lds16(const __bf16* g, __bf16* l) {
    __builtin_amdgcn_global_load_lds(
        (const __attribute__((address_space(1))) void*)g,
        (__attribute__((address_space(3))) void*)l, 16, 0, 0);
}

// ---------------------------------------------------------------------------
// RoPE tables: cos/sin (N x 32), fp64 for fidelity
// ---------------------------------------------------------------------------
__global__ void rope_tables(float* __restrict__ cosT, float* __restrict__ sinT) {
    int idx = blockIdx.x * blockDim.x + threadIdx.x;   // N*32 = 65536
    if (idx >= Nc * 32) return;
    int n = idx >> 5;
    int j = idx & 31;
    double inv = pow(10000.0, -(double)j / 32.0);
    double ang = (double)n * inv;
    cosT[idx] = (float)cos(ang);
    sinT[idx] = (float)sin(ang);
}

// ---------------------------------------------------------------------------
// pack_hl: fp32 -> bf16 hi/lo, same layout. One float4 per thread.
// ---------------------------------------------------------------------------
__global__ __launch_bounds__(256) void pack_hl(
    const float* __restrict__ src, __bf16* __restrict__ h,
    __bf16* __restrict__ l, int n4) {
    int i = blockIdx.x * 256 + threadIdx.x;
    if (i >= n4) return;
    float4 v = ((const float4*)src)[i];
    __bf16 h0 = (__bf16)v.x, h1 = (__bf16)v.y, h2 = (__bf16)v.z, h3 = (__bf16)v.w;
    bf16x4 hv = {h0, h1, h2, h3};
    bf16x4 lv = {(__bf16)(v.x - (float)h0), (__bf16)(v.y - (float)h1),
                 (__bf16)(v.z - (float)h2), (__bf16)(v.w - (float)h3)};
    ((bf16x4*)h)[i] = hv;
    ((bf16x4*)l)[i] = lv;
}

// ---------------------------------------------------------------------------
// pack_hl_T: fp32 src[K][Nn] -> bf16 hi/lo transposed [Nn][K] (LDS 64x64).
// ---------------------------------------------------------------------------
__global__ __launch_bounds__(256) void pack_hl_T(
    const float* __restrict__ src, __bf16* __restrict__ h,
    __bf16* __restrict__ l, int K, int Nn) {
    __shared__ float t[64][65];
    const int k0 = blockIdx.y * 64, n0 = blockIdx.x * 64;
    const int c = threadIdx.x & 63, r4 = threadIdx.x >> 6;
    #pragma unroll 4
    for (int p = 0; p < 16; ++p) {
        int kr = p * 4 + r4;
        t[c][kr] = src[(size_t)(k0 + kr) * Nn + n0 + c];   // t[n][k]
    }
    __syncthreads();
    #pragma unroll 4
    for (int p = 0; p < 16; ++p) {
        int nr = p * 4 + r4;
        float v = t[nr][c];
        __bf16 hi = (__bf16)v;
        size_t o = (size_t)(n0 + nr) * K + k0 + c;
        h[o] = hi;
        l[o] = (__bf16)(v - (float)hi);
    }
}

// ---------------------------------------------------------------------------
// gemm_bf3: fp32-accuracy GEMM on matrix cores via split-bf16 (Markidis).
// C[M][N] = (Ah+Al)[M][K] . (Bh+Bl)^T[N][K]  (+bias), 3 MFMA per frag pair
// (hh + hl + lh; ll term ~2^-32, dropped).
// 128x128 tile, BK=32, 4 waves x (64x64), global_load_lds width-16 staging.
// LDS tile layout (from lane i -> base + i*16): addr(row,kq) =
//   (row>>4)*512 + kq*128 + (row&15)*8  bf16 elems -> frag reads are
//   16 consecutive 16B blocks (all 32 banks, 2-way = free).
// ---------------------------------------------------------------------------
#define MFMA16(A, B, C) __builtin_amdgcn_mfma_f32_16x16x32_bf16(A, B, C, 0, 0, 0)

__global__ __launch_bounds__(256) void gemm_bf3(
    const __bf16* __restrict__ Ah, const __bf16* __restrict__ Al,
    const __bf16* __restrict__ Bh, const __bf16* __restrict__ Bl,
    const float* __restrict__ bias, float* __restrict__ C,
    int M, int N, int K) {
    __shared__ __bf16 sm[4][4096];      // Ah, Al, Bh, Bl tiles: 8 KB each

    const int w = threadIdx.x >> 6;
    const int lane = threadIdx.x & 63;
    const int l16 = lane & 15, quad = lane >> 4;
    const int row0 = blockIdx.y * 128;
    const int col0 = blockIdx.x * 128;
    const int wr = (w >> 1) * 64, wc = (w & 1) * 64;

    // staging: wave w owns tile w (0:Ah 1:Al 2:Bh 3:Bl)
    const __bf16* tsrc = (w == 0) ? Ah : (w == 1) ? Al : (w == 2) ? Bh : Bl;
    const int srow0 = (w < 2) ? row0 : col0;
    __bf16* tdst = sm[w];
    const size_t loff = (size_t)(lane & 15) * K + (lane >> 4) * 8;
    const __bf16* gbase = tsrc + (size_t)srow0 * K + loff;

    f32x4 acc[4][4];
    #pragma unroll
    for (int mi = 0; mi < 4; ++mi)
        #pragma unroll
        for (int ni = 0; ni < 4; ++ni) acc[mi][ni] = (f32x4){0.f, 0.f, 0.f, 0.f};

    for (int k0 = 0; k0 < K; k0 += 32) {
        __syncthreads();                  // previous tile fully consumed
        #pragma unroll
        for (int t = 0; t < 8; ++t)
            gload_lds16(gbase + (size_t)t * 16 * K + k0, &tdst[t * 512]);
        __syncthreads();                  // staging drained (vmcnt0 at barrier)

        bf16x8 ah[4], al[4], bh[4], bl[4];
        #pragma unroll
        for (int i = 0; i < 4; ++i) {
            int ia = (wr / 16 + i) * 512 + quad * 128 + l16 * 8;
            int ib = (wc / 16 + i) * 512 + quad * 128 + l16 * 8;
            ah[i] = *(const bf16x8*)&sm[0][ia];
            al[i] = *(const bf16x8*)&sm[1][ia];
            bh[i] = *(const bf16x8*)&sm[2][ib];
            bl[i] = *(const bf16x8*)&sm[3][ib];
        }
        #pragma unroll
        for (int mi = 0; mi < 4; ++mi)
            #pragma unroll
            for (int ni = 0; ni < 4; ++ni) {
                acc[mi][ni] = MFMA16(ah[mi], bl[ni], acc[mi][ni]);
                acc[mi][ni] = MFMA16(al[mi], bh[ni], acc[mi][ni]);
                acc[mi][ni] = MFMA16(ah[mi], bh[ni], acc[mi][ni]);
            }
    }

    // epilogue: C/D layout row=quad*4+r, col=l16
    #pragma unroll
    for (int mi = 0; mi < 4; ++mi)
        #pragma unroll
        for (int ni = 0; ni < 4; ++ni) {
            int col = col0 + wc + ni * 16 + l16;
            float bv = bias ? bias[col] : 0.f;
            #pragma unroll
            for (int r = 0; r < 4; ++r) {
                int row = row0 + wr + mi * 16 + quad * 4 + r;
                C[(size_t)row * N + col] = acc[mi][ni][r] + bv;
            }
        }
}

// ---------------------------------------------------------------------------
// rope_pack: fp32 qkv [B][N][3][H][D] -> RoPE'd q,k split bf16 hi/lo +
// transposed V.  Qh,Ql,Kh,Kl: [BH][N][64]  Vt: [BH][64][N]
// ---------------------------------------------------------------------------
__global__ __launch_bounds__(256) void rope_pack(
    const float* __restrict__ qkv,
    const float* __restrict__ cosT, const float* __restrict__ sinT,
    __bf16* __restrict__ Qh, __bf16* __restrict__ Ql,
    __bf16* __restrict__ Kh, __bf16* __restrict__ Kl,
    __bf16* __restrict__ Vt) {
    constexpr int C3 = 3 * Cc;
    const int bh = blockIdx.y;
    const int b = bh >> 4, h = bh & 15;
    const int n0 = blockIdx.x * 64;
    const int tid = threadIdx.x;

    const int j = tid & 31, rr = tid >> 5;
    #pragma unroll 2
    for (int pass = 0; pass < 8; ++pass) {
        int n = n0 + pass * 8 + rr;
        const float* row = qkv + ((size_t)(b * Nc + n)) * C3 + h * Dc;
        float c = cosT[n * 32 + j];
        float s = sinT[n * 32 + j];
        float q1 = row[j], q2 = row[j + 32];
        float k1 = row[Cc + j], k2 = row[Cc + j + 32];
        float qa = (q1 * c - q2 * s) * 0.125f;
        float qb = (q1 * s + q2 * c) * 0.125f;
        float ka = k1 * c - k2 * s;
        float kb = k1 * s + k2 * c;
        size_t o = ((size_t)bh * Nc + n) * Dc;
        __bf16 t;
        t = (__bf16)qa; Qh[o + j]      = t; Ql[o + j]      = (__bf16)(qa - (float)t);
        t = (__bf16)qb; Qh[o + j + 32] = t; Ql[o + j + 32] = (__bf16)(qb - (float)t);
        t = (__bf16)ka; Kh[o + j]      = t; Kl[o + j]      = (__bf16)(ka - (float)t);
        t = (__bf16)kb; Kh[o + j + 32] = t; Kl[o + j + 32] = (__bf16)(kb - (float)t);
    }

    __shared__ float vt[64][65];
    const int f = tid & 63, r4 = tid >> 6;
    #pragma unroll 4
    for (int pass = 0; pass < 16; ++pass) {
        int i = pass * 4 + r4;
        vt[f][i] = qkv[((size_t)(b * Nc + n0 + i)) * C3 + 2 * Cc + h * Dc + f];
    }
    __syncthreads();
    #pragma unroll 4
    for (int pass = 0; pass < 16; ++pass) {
        int feat = pass * 4 + r4;
        Vt[((size_t)bh * Dc + feat) * Nc + n0 + f] = (__bf16)vt[feat][f];
    }
}

// ---------------------------------------------------------------------------
// attn_mfma: flash attention on matrix cores (R4 structure, passed).
// Epilogue now writes bf16 hi/lo (Aoh, Aol) [B*N][C] for the proj GEMM.
// ---------------------------------------------------------------------------
__global__ __launch_bounds__(256) void attn_mfma(
    const __bf16* __restrict__ Qh, const __bf16* __restrict__ Ql,
    const __bf16* __restrict__ Kh, const __bf16* __restrict__ Kl,
    const __bf16* __restrict__ Vt,
    __bf16* __restrict__ Aoh, __bf16* __restrict__ Aol) {
    const int bh = blockIdx.y;
    const int b = bh >> 4, h = bh & 15;
    const int q0 = blockIdx.x * 128;
    const int w = threadIdx.x >> 6;
    const int lane = threadIdx.x & 63;
    const int l16 = lane & 15, quad = lane >> 4;

    const __bf16* Qhb = Qh + (size_t)bh * Nc * Dc;
    const __bf16* Qlb = Ql + (size_t)bh * Nc * Dc;
    const __bf16* Khb = Kh + (size_t)bh * Nc * Dc;
    const __bf16* Klb = Kl + (size_t)bh * Nc * Dc;
    const __bf16* Vtb = Vt + (size_t)bh * Dc * Nc;

    bf16x8 qh[2][2], ql[2][2];
    #pragma unroll
    for (int mi = 0; mi < 2; ++mi)
        #pragma unroll
        for (int ks = 0; ks < 2; ++ks) {
            size_t off = (size_t)(q0 + w * 32 + mi * 16 + l16) * Dc + ks * 32 + quad * 8;
            qh[mi][ks] = *(const bf16x8*)(Qhb + off);
            ql[mi][ks] = *(const bf16x8*)(Qlb + off);
        }

    f32x4 Oa[2][4];
    #pragma unroll
    for (int mi = 0; mi < 2; ++mi)
        #pragma unroll
        for (int ni = 0; ni < 4; ++ni) Oa[mi][ni] = (f32x4){0.f, 0.f, 0.f, 0.f};
    float mrow[2][4], lrow[2][4];
    #pragma unroll
    for (int mi = 0; mi < 2; ++mi)
        #pragma unroll
        for (int r = 0; r < 4; ++r) { mrow[mi][r] = -1e30f; lrow[mi][r] = 0.f; }

    __shared__ __bf16 Plds[4][32 * 72];
    __bf16* Pw = Plds[w];

    for (int t = 0; t < Nc; t += 64) {
        f32x4 S[2][4];
        #pragma unroll
        for (int mi = 0; mi < 2; ++mi)
            #pragma unroll
            for (int kt = 0; kt < 4; ++kt) S[mi][kt] = (f32x4){0.f, 0.f, 0.f, 0.f};

        #pragma unroll
        for (int kt = 0; kt < 4; ++kt) {
            size_t kb = (size_t)(t + kt * 16 + l16) * Dc + quad * 8;
            bf16x8 kh0 = *(const bf16x8*)(Khb + kb);
            bf16x8 kh1 = *(const bf16x8*)(Khb + kb + 32);
            bf16x8 kl0 = *(const bf16x8*)(Klb + kb);
            bf16x8 kl1 = *(const bf16x8*)(Klb + kb + 32);
            #pragma unroll
            for (int mi = 0; mi < 2; ++mi) {
                S[mi][kt] = MFMA16(ql[mi][0], kh0, S[mi][kt]);
                S[mi][kt] = MFMA16(qh[mi][0], kl0, S[mi][kt]);
                S[mi][kt] = MFMA16(qh[mi][0], kh0, S[mi][kt]);
                S[mi][kt] = MFMA16(ql[mi][1], kh1, S[mi][kt]);
                S[mi][kt] = MFMA16(qh[mi][1], kl1, S[mi][kt]);
                S[mi][kt] = MFMA16(qh[mi][1], kh1, S[mi][kt]);
            }
        }

        float corr[2][4], psum[2][4];
        #pragma unroll
        for (int mi = 0; mi < 2; ++mi)
            #pragma unroll
            for (int r = 0; r < 4; ++r) {
                float mx = S[mi][0][r];
                mx = fmaxf(mx, S[mi][1][r]);
                mx = fmaxf(mx, S[mi][2][r]);
                mx = fmaxf(mx, S[mi][3][r]);
                mx = fmaxf(mx, __shfl_xor(mx, 1));
                mx = fmaxf(mx, __shfl_xor(mx, 2));
                mx = fmaxf(mx, __shfl_xor(mx, 4));
                mx = fmaxf(mx, __shfl_xor(mx, 8));
                float mn = fmaxf(mrow[mi][r], mx);
                corr[mi][r] = __expf(mrow[mi][r] - mn);
                mrow[mi][r] = mn;
                psum[mi][r] = 0.f;
            }

        #pragma unroll
        for (int mi = 0; mi < 2; ++mi)
            #pragma unroll
            for (int kt = 0; kt < 4; ++kt)
                #pragma unroll
                for (int r = 0; r < 4; ++r) {
                    float p = __expf(S[mi][kt][r] - mrow[mi][r]);
                    __bf16 pb = (__bf16)p;
                    Pw[(mi * 16 + quad * 4 + r) * 72 + kt * 16 + l16] = pb;
                    psum[mi][r] += (float)pb;
                }

        #pragma unroll
        for (int mi = 0; mi < 2; ++mi)
            #pragma unroll
            for (int r = 0; r < 4; ++r) {
                float ps = psum[mi][r];
                ps += __shfl_xor(ps, 1);
                ps += __shfl_xor(ps, 2);
                ps += __shfl_xor(ps, 4);
                ps += __shfl_xor(ps, 8);
                lrow[mi][r] = lrow[mi][r] * corr[mi][r] + ps;
            }

        #pragma unroll
        for (int mi = 0; mi < 2; ++mi)
            #pragma unroll
            for (int ni = 0; ni < 4; ++ni)
                #pragma unroll
                for (int r = 0; r < 4; ++r) Oa[mi][ni][r] *= corr[mi][r];

        #pragma unroll
        for (int ks2 = 0; ks2 < 2; ++ks2) {
            bf16x8 Pf[2];
            #pragma unroll
            for (int mi = 0; mi < 2; ++mi)
                Pf[mi] = *(const bf16x8*)&Pw[(mi * 16 + l16) * 72 + ks2 * 32 + quad * 8];
            #pragma unroll
            for (int ni = 0; ni < 4; ++ni) {
                bf16x8 vf = *(const bf16x8*)(Vtb + (size_t)(ni * 16 + l16) * Nc
                                             + t + ks2 * 32 + quad * 8);
                #pragma unroll
                for (int mi = 0; mi < 2; ++mi)
                    Oa[mi][ni] = MFMA16(Pf[mi], vf, Oa[mi][ni]);
            }
        }
    }

    // epilogue: normalize, split hi/lo, write Aoh/Aol [B*N][C] bf16
    #pragma unroll
    for (int mi = 0; mi < 2; ++mi) {
        float inv[4];
        #pragma unroll
        for (int r = 0; r < 4; ++r) inv[r] = 1.f / lrow[mi][r];
        #pragma unroll
        for (int ni = 0; ni < 4; ++ni)
            #pragma unroll
            for (int r = 0; r < 4; ++r) {
                int row = q0 + w * 32 + mi * 16 + quad * 4 + r;
                size_t off = ((size_t)(b * Nc + row)) * Cc + h * Dc + ni * 16 + l16;
                float v = Oa[mi][ni][r] * inv[r];
                __bf16 hi = (__bf16)v;
                Aoh[off] = hi;
                Aol[off] = (__bf16)(v - (float)hi);
            }
    }
}

// ---------------------------------------------------------------------------
extern "C" void kernel_launch(void* const* d_in, const int* in_sizes, int n_in,
                              void* d_out, int out_size, void* d_ws, size_t ws_size,
                              hipStream_t stream) {
    const float* x      = (const float*)d_in[0];   // (2,2048,1024)
    const float* w_qkv  = (const float*)d_in[1];   // (1024,3072)
    const float* w_proj = (const float*)d_in[2];   // (1024,1024)
    const float* b_proj = (const float*)d_in[3];   // (1024,)
    float* out = (float*)d_out;                    // (2,2048,1024)

    float* ws = (float*)d_ws;
    float* qkv  = ws;                                  // 12,582,912 f (50.3 MB)
    float* cosT = qkv + (size_t)4096 * 3072;           //     65,536 f
    float* sinT = cosT + Nc * 32;                      //     65,536 f
    __bf16* bf = (__bf16*)(sinT + Nc * 32);
    constexpr size_t HS = (size_t)Bc * Hc * Nc * Dc;   // 4,194,304
    __bf16* Qh  = bf;                                  // [BH][N][64]
    __bf16* Ql  = Qh + HS;
    __bf16* Kh  = Ql + HS;
    __bf16* Kl  = Kh + HS;
    __bf16* Vt  = Kl + HS;                             // [BH][64][N]
    __bf16* Xh  = Vt + HS;                             // x hi/lo [4096][1024]
    __bf16* Xl  = Xh + HS;                             //   (reused as Aoh/Aol)
    __bf16* Aoh = Xh;
    __bf16* Aol = Xl;
    __bf16* Wqh = Xl + HS;                             // w_qkv^T [3072][1024]
    __bf16* Wql = Wqh + (size_t)3072 * 1024;
    __bf16* Wph = Wqh;                                 // w_proj^T [1024][1024]
    __bf16* Wpl = Wqh + (size_t)1024 * 1024;           //   (reused region)
    // total: ~122.2 MB

    // 1. RoPE tables + input packs
    rope_tables<<<(Nc * 32 + 255) / 256, 256, 0, stream>>>(cosT, sinT);
    pack_hl<<<(int)(HS / 4 / 256), 256, 0, stream>>>(x, Xh, Xl, (int)(HS / 4));
    pack_hl_T<<<dim3(3072 / 64, 1024 / 64), 256, 0, stream>>>(
        w_qkv, Wqh, Wql, 1024, 3072);

    // 2. qkv = x @ w_qkv  (split-bf16 MFMA, fp32 out)
    gemm_bf3<<<dim3(3072 / 128, 4096 / 128), 256, 0, stream>>>(
        Xh, Xl, Wqh, Wql, nullptr, qkv, 4096, 3072, 1024);

    // 3. proj weight pack (reuses Wq region — after qkv GEMM)
    pack_hl_T<<<dim3(1024 / 64, 1024 / 64), 256, 0, stream>>>(
        w_proj, Wph, Wpl, 1024, 1024);

    // 4. RoPE + bf16 hi/lo split + V transpose
    rope_pack<<<dim3(Nc / 64, Bc * Hc), 256, 0, stream>>>(
        qkv, cosT, sinT, Qh, Ql, Kh, Kl, Vt);

    // 5. MFMA flash attention -> Ao hi/lo bf16 [B*N][C]
    attn_mfma<<<dim3(Nc / 128, Bc * Hc), 256, 0, stream>>>(
        Qh, Ql, Kh, Kl, Vt, Aoh, Aol);

    // 6. out = attn_out @ w_proj + b_proj  (split-bf16 MFMA, fp32 out)
    gemm_bf3<<<dim3(1024 / 128, 4096 / 128), 256, 0, stream>>>(
        Aoh, Aol, Wph, Wpl, b_proj, out, 4096, 1024, 1024);
}